// Round 15
// baseline (200.825 us; speedup 1.0000x reference)
//
#include <hip/hip_runtime.h>
#include <hip/hip_bf16.h>

#define N_NODES 200000
#define N_EDGES 3200000
#define FEATS   256
#define NC      32

#define NBPB    128                      // nodes per fine bucket (dst >> 7)
#define BUCKETS 1563                     // fine buckets
#define CAP     2560                     // fine capacity (mean 2048, +11 sigma)

#define NCOARSE 25                       // coarse buckets (dst >> 13, 8192 nodes)
#define CHUNKS1 33                       // pass-2 chunks per coarse region
#define CAP1    (CHUNKS1 * 4096)         // 135168: mean 131072 (!), +11.6 sigma

typedef __attribute__((ext_vector_type(8))) short bf16x8;
typedef __attribute__((ext_vector_type(4))) float f32x4;

__device__ __forceinline__ float atomAddF(float* p, float v) {
    return unsafeAtomicAdd(p, v);
}
__device__ __forceinline__ short f2bf(float f) {
    return (short)__bfloat16_as_ushort(__float2bfloat16(f));
}

// ---------------------------------------------------------------------------
// Kernel 1: h = x @ W^T + bias via bf16 MFMA; h stored as BF16.
// Fused: S1[c] += (u[n]/N)*h[n,c], S2 += (...)^2  (proven round 8, ~48us)
// ---------------------------------------------------------------------------
__global__ __launch_bounds__(256, 3) void k_linear(
    const float* __restrict__ x, const float* __restrict__ Wmat,
    const float* __restrict__ bias, const float* __restrict__ u_sum,
    ushort* __restrict__ h_bf, float* __restrict__ S1, float* __restrict__ S2)
{
    __shared__ float lds_s1[4][32];
    __shared__ float lds_s2[4];

    const int lane = threadIdx.x & 63;
    const int wv   = threadIdx.x >> 6;
    const int lr   = lane & 15;
    const int kc   = lane >> 4;

    bf16x8 bfr[8][2];
    #pragma unroll
    for (int ct = 0; ct < 2; ++ct) {
        const float* wp = Wmat + (size_t)(ct * 16 + lr) * FEATS + kc * 8;
        #pragma unroll
        for (int kt = 0; kt < 8; ++kt) {
            f32x4 v0 = *(const f32x4*)(wp + kt * 32);
            f32x4 v1 = *(const f32x4*)(wp + kt * 32 + 4);
            bf16x8 b;
            b[0]=f2bf(v0.x); b[1]=f2bf(v0.y); b[2]=f2bf(v0.z); b[3]=f2bf(v0.w);
            b[4]=f2bf(v1.x); b[5]=f2bf(v1.y); b[6]=f2bf(v1.z); b[7]=f2bf(v1.w);
            bfr[kt][ct] = b;
        }
    }

    const float bias0 = bias[lr], bias1 = bias[16 + lr];
    const float invn = 1.0f / (float)N_NODES;
    float s1_0 = 0.f, s1_1 = 0.f, s2 = 0.f;

    const int ntiles = N_NODES / 16;
    for (int t = blockIdx.x * 4 + wv; t < ntiles; t += gridDim.x * 4) {
        const int base = t * 16;
        const float* xp = x + (size_t)(base + lr) * FEATS + kc * 8;
        f32x4 acc0 = {bias0, bias0, bias0, bias0};
        f32x4 acc1 = {bias1, bias1, bias1, bias1};
        #pragma unroll
        for (int kt = 0; kt < 8; ++kt) {
            f32x4 v0 = *(const f32x4*)(xp + kt * 32);
            f32x4 v1 = *(const f32x4*)(xp + kt * 32 + 4);
            bf16x8 a;
            a[0]=f2bf(v0.x); a[1]=f2bf(v0.y); a[2]=f2bf(v0.z); a[3]=f2bf(v0.w);
            a[4]=f2bf(v1.x); a[5]=f2bf(v1.y); a[6]=f2bf(v1.z); a[7]=f2bf(v1.w);
            acc0 = __builtin_amdgcn_mfma_f32_16x16x32_bf16(a, bfr[kt][0], acc0, 0, 0, 0);
            acc1 = __builtin_amdgcn_mfma_f32_16x16x32_bf16(a, bfr[kt][1], acc1, 0, 0, 0);
        }
        #pragma unroll
        for (int i = 0; i < 4; ++i) {
            const int row = base + kc * 4 + i;
            h_bf[(size_t)row * NC + lr]      = (ushort)f2bf(acc0[i]);
            h_bf[(size_t)row * NC + 16 + lr] = (ushort)f2bf(acc1[i]);
            const float um = u_sum[row] * invn;
            float a0 = um * acc0[i], a1 = um * acc1[i];
            s1_0 += a0; s1_1 += a1;
            s2 += a0 * a0 + a1 * a1;
        }
    }

    s1_0 += __shfl_xor(s1_0, 16); s1_0 += __shfl_xor(s1_0, 32);
    s1_1 += __shfl_xor(s1_1, 16); s1_1 += __shfl_xor(s1_1, 32);
    #pragma unroll
    for (int off = 1; off < 64; off <<= 1) s2 += __shfl_xor(s2, off);
    if (lane < 16) { lds_s1[wv][lr] = s1_0; lds_s1[wv][16 + lr] = s1_1; }
    if (lane == 0) lds_s2[wv] = s2;
    __syncthreads();
    if (threadIdx.x < 32) {
        float t4 = lds_s1[0][threadIdx.x] + lds_s1[1][threadIdx.x]
                 + lds_s1[2][threadIdx.x] + lds_s1[3][threadIdx.x];
        atomAddF(&S1[threadIdx.x], t4);
    }
    if (threadIdx.x == 32)
        atomAddF(S2, lds_s2[0] + lds_s2[1] + lds_s2[2] + lds_s2[3]);
}

// ---------------------------------------------------------------------------
// Radix pass 1: 25-way coarse split (dst >> 13). 391 blocks x 8192 edges.
// Reserve = 25 atomics/block (9.8k total). Stores land in 25 hot
// line-streams per block -> L2 write-combines to full lines.
// payload: x = src | (dst&8191)<<18  (18+13 = 31 bits)
// ---------------------------------------------------------------------------
__global__ __launch_bounds__(512) void k_pass1(
    const int* __restrict__ src, const float* __restrict__ w,
    const int* __restrict__ dst, int* __restrict__ pos1,
    int2* __restrict__ coarse)
{
    __shared__ int hist[NCOARSE];
    __shared__ int cursor[NCOARSE];
    const int tid = threadIdx.x;
    if (tid < NCOARSE) hist[tid] = 0;
    __syncthreads();

    const int E4 = N_EDGES / 4;
    const int t4 = blockIdx.x * 2048;
    int4 dd[4];
    #pragma unroll
    for (int i = 0; i < 4; ++i) {
        int e4 = t4 + i * 512 + tid;
        if (e4 < E4) {
            int4 d = ((const int4*)dst)[e4];
            dd[i] = d;
            atomicAdd(&hist[d.x >> 13], 1);
            atomicAdd(&hist[d.y >> 13], 1);
            atomicAdd(&hist[d.z >> 13], 1);
            atomicAdd(&hist[d.w >> 13], 1);
        } else dd[i].x = -1;
    }
    __syncthreads();
    if (tid < NCOARSE) {
        int hc = hist[tid];
        cursor[tid] = hc ? (tid * CAP1 + atomicAdd(&pos1[tid], hc)) : 0;
    }
    __syncthreads();
    #pragma unroll
    for (int i = 0; i < 4; ++i) {
        int e4 = t4 + i * 512 + tid;
        if (dd[i].x >= 0) {
            int4   s4 = ((const int4*)src)[e4];
            float4 w4 = ((const float4*)w)[e4];
            int d, q; int2 v;
            d = dd[i].x; q = atomicAdd(&cursor[d >> 13], 1);
            v.x = s4.x | ((d & 8191) << 18); v.y = __float_as_int(w4.x);
            coarse[q] = v;
            d = dd[i].y; q = atomicAdd(&cursor[d >> 13], 1);
            v.x = s4.y | ((d & 8191) << 18); v.y = __float_as_int(w4.y);
            coarse[q] = v;
            d = dd[i].z; q = atomicAdd(&cursor[d >> 13], 1);
            v.x = s4.z | ((d & 8191) << 18); v.y = __float_as_int(w4.z);
            coarse[q] = v;
            d = dd[i].w; q = atomicAdd(&cursor[d >> 13], 1);
            v.x = s4.w | ((d & 8191) << 18); v.y = __float_as_int(w4.w);
            coarse[q] = v;
        }
    }
}

// ---------------------------------------------------------------------------
// Radix pass 2: 64-way fine split within each coarse region. 25x33 = 825
// blocks x 4096 edges, coalesced reads, ~51k reserve atomics total.
// Emits breduce's payload: x = src | (dst&127)<<18.
// ---------------------------------------------------------------------------
__global__ __launch_bounds__(512) void k_pass2(
    const int2* __restrict__ coarse, const int* __restrict__ pos1,
    int* __restrict__ pos2, int2* __restrict__ fine)
{
    __shared__ int hist[64];
    __shared__ int cursor[64];
    const int c     = blockIdx.x / CHUNKS1;      // 0..24
    const int chunk = blockIdx.x % CHUNKS1;      // 0..32
    const int tid   = threadIdx.x;
    if (tid < 64) hist[tid] = 0;
    __syncthreads();

    int n_c = pos1[c];
    if (n_c > CAP1) n_c = CAP1;
    const int base = c * CAP1 + chunk * 4096;
    const int lim  = c * CAP1 + n_c;

    int2 pr[8];
    int  lf[8];
    #pragma unroll
    for (int i = 0; i < 8; ++i) {
        int idx = base + i * 512 + tid;
        if (idx < lim) {
            pr[i] = coarse[idx];
            lf[i] = (int)(((unsigned)pr[i].x >> 18) >> 7);   // local fine 0..63
            atomicAdd(&hist[lf[i]], 1);
        } else lf[i] = -1;
    }
    __syncthreads();
    if (tid < 64) {
        int hc = hist[tid];
        int f  = c * 64 + tid;                // global fine id = dst>>7
        cursor[tid] = hc ? (f * CAP + atomicAdd(&pos2[f], hc)) : 0;
    }
    __syncthreads();
    #pragma unroll
    for (int i = 0; i < 8; ++i) {
        if (lf[i] >= 0) {
            int q = atomicAdd(&cursor[lf[i]], 1);
            int dstlow = (int)((unsigned)pr[i].x >> 18);     // 13 bits
            int2 v;
            v.x = (pr[i].x & 0x3FFFF) | ((dstlow & 127) << 18);
            v.y = pr[i].y;
            fine[q] = v;
        }
    }
}

// ---------------------------------------------------------------------------
// Per-bucket: payloads read ONCE into registers (5/thread), in-LDS counting
// sort to per-node CSR, then per-node register gather with 4-wide unrolled
// independent h-line loads. (proven ~45us, round 9)
// ---------------------------------------------------------------------------
__global__ __launch_bounds__(512) void k_breduce(
    const int2* __restrict__ bucketed, const int* __restrict__ pos,
    const ushort* __restrict__ h_bf,
    float* __restrict__ y, float* __restrict__ colsum)
{
    __shared__ int2  eSort[CAP];         // 20 KB
    __shared__ int   scnt[NBPB];
    __shared__ int   soffs[NBPB];
    __shared__ int   scur[NBPB];
    __shared__ int   ssc[NBPB];
    __shared__ float red[512];

    const int tid = threadIdx.x;
    const int b   = blockIdx.x;
    const int beg = b * CAP;
    int n = pos[b];
    if (n > CAP) n = CAP;

    if (tid < NBPB) scnt[tid] = 0;
    __syncthreads();

    int2 pr0, pr1, pr2, pr3, pr4;
    int  l0 = -1, l1 = -1, l2 = -1, l3 = -1, l4 = -1;
    if (tid          < n) { pr0 = bucketed[beg + tid];          l0 = (unsigned)pr0.x >> 18; }
    if (tid +  512   < n) { pr1 = bucketed[beg + tid + 512];    l1 = (unsigned)pr1.x >> 18; }
    if (tid + 1024   < n) { pr2 = bucketed[beg + tid + 1024];   l2 = (unsigned)pr2.x >> 18; }
    if (tid + 1536   < n) { pr3 = bucketed[beg + tid + 1536];   l3 = (unsigned)pr3.x >> 18; }
    if (tid + 2048   < n) { pr4 = bucketed[beg + tid + 2048];   l4 = (unsigned)pr4.x >> 18; }
    if (l0 >= 0) atomicAdd(&scnt[l0], 1);
    if (l1 >= 0) atomicAdd(&scnt[l1], 1);
    if (l2 >= 0) atomicAdd(&scnt[l2], 1);
    if (l3 >= 0) atomicAdd(&scnt[l3], 1);
    if (l4 >= 0) atomicAdd(&scnt[l4], 1);
    __syncthreads();

    if (tid < NBPB) ssc[tid] = scnt[tid];
    __syncthreads();
    for (int off = 1; off < NBPB; off <<= 1) {
        int t = 0;
        if (tid < NBPB && tid >= off) t = ssc[tid - off];
        __syncthreads();
        if (tid < NBPB && tid >= off) ssc[tid] += t;
        __syncthreads();
    }
    if (tid < NBPB) {
        int o = ssc[tid] - scnt[tid];
        soffs[tid] = o;
        scur[tid]  = o;
    }
    __syncthreads();

    if (l0 >= 0) { int q = atomicAdd(&scur[l0], 1); eSort[q] = pr0; }
    if (l1 >= 0) { int q = atomicAdd(&scur[l1], 1); eSort[q] = pr1; }
    if (l2 >= 0) { int q = atomicAdd(&scur[l2], 1); eSort[q] = pr2; }
    if (l3 >= 0) { int q = atomicAdd(&scur[l3], 1); eSort[q] = pr3; }
    if (l4 >= 0) { int q = atomicAdd(&scur[l4], 1); eSort[q] = pr4; }
    __syncthreads();

    const __hip_bfloat16* hb = (const __hip_bfloat16*)h_bf;
    const int c = tid & 31;
    const int g = tid >> 5;              // 0..15
    float scol = 0.f;
    for (int ld = g; ld < NBPB; ld += 16) {
        const int node = b * NBPB + ld;
        if (node >= N_NODES) break;
        int j = soffs[ld];
        const int e = j + scnt[ld];
        float s = 0.f;
        for (; j + 4 <= e; j += 4) {
            int2 p0 = eSort[j], p1 = eSort[j + 1], p2 = eSort[j + 2], p3 = eSort[j + 3];
            float h0 = __bfloat162float(hb[(size_t)(p0.x & 0x3FFFF) * NC + c]);
            float h1 = __bfloat162float(hb[(size_t)(p1.x & 0x3FFFF) * NC + c]);
            float h2 = __bfloat162float(hb[(size_t)(p2.x & 0x3FFFF) * NC + c]);
            float h3 = __bfloat162float(hb[(size_t)(p3.x & 0x3FFFF) * NC + c]);
            s = fmaf(h0, __int_as_float(p0.y), s);
            s = fmaf(h1, __int_as_float(p1.y), s);
            s = fmaf(h2, __int_as_float(p2.y), s);
            s = fmaf(h3, __int_as_float(p3.y), s);
        }
        for (; j < e; ++j) {
            int2 p = eSort[j];
            float hv = __bfloat162float(hb[(size_t)(p.x & 0x3FFFF) * NC + c]);
            s = fmaf(hv, __int_as_float(p.y), s);
        }
        y[(size_t)node * NC + c] = s;
        scol += s;
    }

    red[tid] = scol;
    __syncthreads();
    if (tid < 32) {
        float t = 0.f;
        #pragma unroll
        for (int jj = 0; jj < 16; ++jj) t += red[tid + 32 * jj];
        atomAddF(&colsum[tid], t);
    }
}

// ---------------------------------------------------------------------------
// Fallback path (small workspace): atomic scatter + colsum
// ---------------------------------------------------------------------------
__global__ __launch_bounds__(256) void k_scatter_atomic(
    const ushort* __restrict__ h_bf, const float* __restrict__ w,
    const int* __restrict__ src, const int* __restrict__ dst,
    float* __restrict__ y)
{
    const __hip_bfloat16* hb = (const __hip_bfloat16*)h_bf;
    const long long total  = (long long)N_EDGES * NC;
    const long long stride = (long long)gridDim.x * 256;
    for (long long i = (long long)blockIdx.x * 256 + threadIdx.x;
         i < total; i += stride) {
        const int e = (int)(i >> 5);
        const int c = (int)(i & 31);
        float hv = __bfloat162float(hb[(size_t)src[e] * NC + c]);
        atomAddF(&y[(size_t)dst[e] * NC + c], hv * w[e]);
    }
}

__global__ __launch_bounds__(256) void k_colsum(
    const float* __restrict__ y, float* __restrict__ colsum)
{
    __shared__ float red[256];
    const long long total  = (long long)N_NODES * NC;
    const long long stride = (long long)gridDim.x * 256;
    float s = 0.f;
    for (long long i = (long long)blockIdx.x * 256 + threadIdx.x;
         i < total; i += stride)
        s += y[i];
    red[threadIdx.x] = s;
    __syncthreads();
    if (threadIdx.x < 32) {
        float t = 0.f;
        #pragma unroll
        for (int j = 0; j < 8; ++j) t += red[threadIdx.x + 32 * j];
        atomAddF(&colsum[threadIdx.x], t);
    }
}

// ---------------------------------------------------------------------------
// loss; acc: [0..31] colsum_y, [32..63] S1, [64] S2
// ---------------------------------------------------------------------------
__global__ void k_final(const float* __restrict__ acc, float* __restrict__ loss_out)
{
    double cross = 0.0, msq = 0.0;
    for (int c = 0; c < NC; ++c) {
        double m = (double)acc[c] / (double)N_NODES;
        cross += m * (double)acc[32 + c];
        msq   += m * m;
    }
    double loss = ((double)acc[64] - 2.0 * cross + (double)N_NODES * msq)
                  / ((double)N_NODES * (double)NC);
    *loss_out = (float)loss;
}

extern "C" void kernel_launch(void* const* d_in, const int* in_sizes, int n_in,
                              void* d_out, int out_size, void* d_ws, size_t ws_size,
                              hipStream_t stream)
{
    const float* x   = (const float*)d_in[0];
    const float* w   = (const float*)d_in[1];
    const float* u   = (const float*)d_in[2];
    const float* Wm  = (const float*)d_in[3];
    const float* Wb  = (const float*)d_in[4];
    const int*   src = (const int*)d_in[5];
    const int*   dst = (const int*)d_in[6];

    float* out = (float*)d_out;                  // y [N*32] then loss [1]

    uint8_t* w8 = (uint8_t*)d_ws;
    float*  acc  = (float*)w8;                             // 1 KB
    int*    pos2 = (int*)(w8 + 1024);                      // 8 KB (1600 ints)
    int*    pos1 = (int*)(w8 + 1024 + 8192);               // 1 KB (25 ints)
    ushort* h_bf = (ushort*)(w8 + 10240);                  // 12.8 MB
    int2*   fine = (int2*)(w8 + 10240 + (size_t)N_NODES * NC * 2);        // 32 MB
    int2*   coarse = fine + (size_t)BUCKETS * CAP;                        // 27 MB

    const size_t need = 10240 + (size_t)N_NODES * NC * 2
                      + (size_t)BUCKETS * CAP * 8 + (size_t)NCOARSE * CAP1 * 8;

    // zero acc + pos2 + pos1 in one memset
    hipMemsetAsync(w8, 0, 10240, stream);

    if (ws_size >= need) {
        k_linear <<<2048, 256, 0, stream>>>(x, Wm, Wb, u, h_bf, acc + 32, acc + 64);
        k_pass1  <<<391, 512, 0, stream>>>(src, w, dst, pos1, coarse);
        k_pass2  <<<NCOARSE * CHUNKS1, 512, 0, stream>>>(coarse, pos1, pos2, fine);
        k_breduce<<<BUCKETS, 512, 0, stream>>>(fine, pos2, h_bf, out, acc);
    } else {
        hipMemsetAsync(d_out, 0, (size_t)out_size * sizeof(float), stream);
        k_linear        <<<2048, 256, 0, stream>>>(x, Wm, Wb, u, h_bf, acc + 32, acc + 64);
        k_scatter_atomic<<<8192, 256, 0, stream>>>(h_bf, w, src, dst, out);
        k_colsum        <<<2048, 256, 0, stream>>>(out, acc);
    }

    k_final<<<1, 1, 0, stream>>>(acc, out + (size_t)N_NODES * NC);
}

// Round 16
// 186.892 us; speedup vs baseline: 1.0746x; 1.0746x over previous
//
#include <hip/hip_runtime.h>
#include <hip/hip_bf16.h>

#define N_NODES 200000
#define N_EDGES 3200000
#define FEATS   256
#define NC      32

#define NBPB    128                      // nodes per bucket (dst >> 7)
#define BUCKETS 1563                     // ceil(200000 / 128)
#define CAP     2560                     // bucket capacity (mean 2048, +11 sigma)

#define BKT_BLOCKS 391                   // 8192-edge tiles
#define LIN_BLOCKS 512

typedef __attribute__((ext_vector_type(8))) short bf16x8;
typedef __attribute__((ext_vector_type(4))) float f32x4;

__device__ __forceinline__ float atomAddF(float* p, float v) {
    return unsafeAtomicAdd(p, v);
}
__device__ __forceinline__ short f2bf(float f) {
    return (short)__bfloat16_as_ushort(__float2bfloat16(f));
}

// ---------------------------------------------------------------------------
// Fused linear + bucket, striped roles (round-13 base, best known: 187us).
// Bucket path uses RANK-REUSE: the histogram atomicAdd's return value IS the
// edge's intra-(block,bucket) rank -> final pos = base[bucket] + rank. This
// halves the bucket path's LDS atomics (6.4M -> 3.2M).
// ---------------------------------------------------------------------------
__global__ __launch_bounds__(512, 4) void k_fused(
    const float* __restrict__ x, const float* __restrict__ Wmat,
    const float* __restrict__ bias, const float* __restrict__ u_sum,
    ushort* __restrict__ h_bf, float* __restrict__ S1, float* __restrict__ S2,
    const int* __restrict__ src, const float* __restrict__ w,
    const int* __restrict__ dst, int* __restrict__ pos,
    int2* __restrict__ bucketed)
{
    __shared__ int   hist[BUCKETS];
    __shared__ int   basearr[BUCKETS];
    __shared__ float lds_s1[8][32];
    __shared__ float lds_s2[8];

    int rid;
    bool isBucket;
    if (blockIdx.x < 2 * BKT_BLOCKS) {
        isBucket = ((blockIdx.x & 1) == 0);
        rid = blockIdx.x >> 1;
    } else {
        isBucket = false;
        rid = BKT_BLOCKS + (blockIdx.x - 2 * BKT_BLOCKS);
    }

    if (isBucket) {
        // ---------------- bucket path: 8192 edges per block ---------------
        const int tid = threadIdx.x;
        for (int i = tid; i < BUCKETS; i += 512) hist[i] = 0;
        __syncthreads();

        const int E4 = N_EDGES / 4;
        const int t4 = rid * 2048;
        int4 dd[4];
        int  rk[16];
        #pragma unroll
        for (int i = 0; i < 4; ++i) {
            int e4 = t4 + i * 512 + tid;
            if (e4 < E4) {
                int4 d = ((const int4*)dst)[e4];
                dd[i] = d;
                rk[i * 4 + 0] = atomicAdd(&hist[d.x >> 7], 1);
                rk[i * 4 + 1] = atomicAdd(&hist[d.y >> 7], 1);
                rk[i * 4 + 2] = atomicAdd(&hist[d.z >> 7], 1);
                rk[i * 4 + 3] = atomicAdd(&hist[d.w >> 7], 1);
            } else dd[i].x = -1;
        }
        __syncthreads();
        for (int i = tid; i < BUCKETS; i += 512) {
            int hc = hist[i];
            basearr[i] = hc ? (i * CAP + atomicAdd(&pos[i], hc)) : 0;
        }
        __syncthreads();
        #pragma unroll
        for (int i = 0; i < 4; ++i) {
            int e4 = t4 + i * 512 + tid;
            if (dd[i].x >= 0) {
                int4   s4 = ((const int4*)src)[e4];
                float4 w4 = ((const float4*)w)[e4];
                int d, q; int2 v;
                d = dd[i].x; q = basearr[d >> 7] + rk[i * 4 + 0];
                v.x = s4.x | ((d & 127) << 18); v.y = __float_as_int(w4.x);
                bucketed[q] = v;
                d = dd[i].y; q = basearr[d >> 7] + rk[i * 4 + 1];
                v.x = s4.y | ((d & 127) << 18); v.y = __float_as_int(w4.y);
                bucketed[q] = v;
                d = dd[i].z; q = basearr[d >> 7] + rk[i * 4 + 2];
                v.x = s4.z | ((d & 127) << 18); v.y = __float_as_int(w4.z);
                bucketed[q] = v;
                d = dd[i].w; q = basearr[d >> 7] + rk[i * 4 + 3];
                v.x = s4.w | ((d & 127) << 18); v.y = __float_as_int(w4.w);
                bucketed[q] = v;
            }
        }
        return;
    }

    // ---------------------- linear path (8 waves) -------------------------
    const int lane = threadIdx.x & 63;
    const int wv   = threadIdx.x >> 6;      // 0..7
    const int lr   = lane & 15;
    const int kc   = lane >> 4;

    bf16x8 bfr[8][2];
    #pragma unroll
    for (int ct = 0; ct < 2; ++ct) {
        const float* wp = Wmat + (size_t)(ct * 16 + lr) * FEATS + kc * 8;
        #pragma unroll
        for (int kt = 0; kt < 8; ++kt) {
            f32x4 v0 = *(const f32x4*)(wp + kt * 32);
            f32x4 v1 = *(const f32x4*)(wp + kt * 32 + 4);
            bf16x8 b;
            b[0]=f2bf(v0.x); b[1]=f2bf(v0.y); b[2]=f2bf(v0.z); b[3]=f2bf(v0.w);
            b[4]=f2bf(v1.x); b[5]=f2bf(v1.y); b[6]=f2bf(v1.z); b[7]=f2bf(v1.w);
            bfr[kt][ct] = b;
        }
    }

    const float bias0 = bias[lr], bias1 = bias[16 + lr];
    const float invn = 1.0f / (float)N_NODES;
    float s1_0 = 0.f, s1_1 = 0.f, s2 = 0.f;

    const int ntiles = N_NODES / 16;
    for (int t = rid * 8 + wv; t < ntiles; t += LIN_BLOCKS * 8) {
        const int base = t * 16;
        const float* xp = x + (size_t)(base + lr) * FEATS + kc * 8;
        f32x4 acc0 = {bias0, bias0, bias0, bias0};
        f32x4 acc1 = {bias1, bias1, bias1, bias1};
        #pragma unroll
        for (int kt = 0; kt < 8; ++kt) {
            f32x4 v0 = *(const f32x4*)(xp + kt * 32);
            f32x4 v1 = *(const f32x4*)(xp + kt * 32 + 4);
            bf16x8 a;
            a[0]=f2bf(v0.x); a[1]=f2bf(v0.y); a[2]=f2bf(v0.z); a[3]=f2bf(v0.w);
            a[4]=f2bf(v1.x); a[5]=f2bf(v1.y); a[6]=f2bf(v1.z); a[7]=f2bf(v1.w);
            acc0 = __builtin_amdgcn_mfma_f32_16x16x32_bf16(a, bfr[kt][0], acc0, 0, 0, 0);
            acc1 = __builtin_amdgcn_mfma_f32_16x16x32_bf16(a, bfr[kt][1], acc1, 0, 0, 0);
        }
        #pragma unroll
        for (int i = 0; i < 4; ++i) {
            const int row = base + kc * 4 + i;
            h_bf[(size_t)row * NC + lr]      = (ushort)f2bf(acc0[i]);
            h_bf[(size_t)row * NC + 16 + lr] = (ushort)f2bf(acc1[i]);
            const float um = u_sum[row] * invn;
            float a0 = um * acc0[i], a1 = um * acc1[i];
            s1_0 += a0; s1_1 += a1;
            s2 += a0 * a0 + a1 * a1;
        }
    }

    s1_0 += __shfl_xor(s1_0, 16); s1_0 += __shfl_xor(s1_0, 32);
    s1_1 += __shfl_xor(s1_1, 16); s1_1 += __shfl_xor(s1_1, 32);
    #pragma unroll
    for (int off = 1; off < 64; off <<= 1) s2 += __shfl_xor(s2, off);
    if (lane < 16) { lds_s1[wv][lr] = s1_0; lds_s1[wv][16 + lr] = s1_1; }
    if (lane == 0) lds_s2[wv] = s2;
    __syncthreads();
    if (threadIdx.x < 32) {
        float t8 = 0.f;
        #pragma unroll
        for (int j = 0; j < 8; ++j) t8 += lds_s1[j][threadIdx.x];
        atomAddF(&S1[threadIdx.x], t8);
    }
    if (threadIdx.x == 32) {
        float t8 = 0.f;
        #pragma unroll
        for (int j = 0; j < 8; ++j) t8 += lds_s2[j];
        atomAddF(S2, t8);
    }
}

// ---------------------------------------------------------------------------
// Per-bucket reduce with rank-reuse: the scnt atomicAdd's return value is the
// edge's intra-node rank -> eSort pos = soffs[node] + rank (no scur pass).
// Then per-node register gather, 4-wide independent h-line loads.
// ---------------------------------------------------------------------------
__global__ __launch_bounds__(512) void k_breduce(
    const int2* __restrict__ bucketed, const int* __restrict__ pos,
    const ushort* __restrict__ h_bf,
    float* __restrict__ y, float* __restrict__ colsum)
{
    __shared__ int2  eSort[CAP];         // 20 KB
    __shared__ int   scnt[NBPB];
    __shared__ int   soffs[NBPB];
    __shared__ int   ssc[NBPB];
    __shared__ float red[512];

    const int tid = threadIdx.x;
    const int b   = blockIdx.x;
    const int beg = b * CAP;
    int n = pos[b];
    if (n > CAP) n = CAP;

    if (tid < NBPB) scnt[tid] = 0;
    __syncthreads();

    // load payloads + count (atomic return = intra-node rank)
    int2 pr0, pr1, pr2, pr3, pr4;
    int  l0 = -1, l1 = -1, l2 = -1, l3 = -1, l4 = -1;
    int  r0 = 0, r1 = 0, r2 = 0, r3 = 0, r4 = 0;
    if (tid        < n) { pr0 = bucketed[beg + tid];        l0 = (unsigned)pr0.x >> 18; r0 = atomicAdd(&scnt[l0], 1); }
    if (tid +  512 < n) { pr1 = bucketed[beg + tid +  512]; l1 = (unsigned)pr1.x >> 18; r1 = atomicAdd(&scnt[l1], 1); }
    if (tid + 1024 < n) { pr2 = bucketed[beg + tid + 1024]; l2 = (unsigned)pr2.x >> 18; r2 = atomicAdd(&scnt[l2], 1); }
    if (tid + 1536 < n) { pr3 = bucketed[beg + tid + 1536]; l3 = (unsigned)pr3.x >> 18; r3 = atomicAdd(&scnt[l3], 1); }
    if (tid + 2048 < n) { pr4 = bucketed[beg + tid + 2048]; l4 = (unsigned)pr4.x >> 18; r4 = atomicAdd(&scnt[l4], 1); }
    __syncthreads();

    // exclusive scan over 128 counters
    if (tid < NBPB) ssc[tid] = scnt[tid];
    __syncthreads();
    for (int off = 1; off < NBPB; off <<= 1) {
        int t = 0;
        if (tid < NBPB && tid >= off) t = ssc[tid - off];
        __syncthreads();
        if (tid < NBPB && tid >= off) ssc[tid] += t;
        __syncthreads();
    }
    if (tid < NBPB) soffs[tid] = ssc[tid] - scnt[tid];
    __syncthreads();

    // scatter into node-sorted LDS (plain LDS read + add, no atomics)
    if (l0 >= 0) eSort[soffs[l0] + r0] = pr0;
    if (l1 >= 0) eSort[soffs[l1] + r1] = pr1;
    if (l2 >= 0) eSort[soffs[l2] + r2] = pr2;
    if (l3 >= 0) eSort[soffs[l3] + r3] = pr3;
    if (l4 >= 0) eSort[soffs[l4] + r4] = pr4;
    __syncthreads();

    const __hip_bfloat16* hb = (const __hip_bfloat16*)h_bf;
    const int c = tid & 31;
    const int g = tid >> 5;              // 0..15
    float scol = 0.f;
    for (int ld = g; ld < NBPB; ld += 16) {
        const int node = b * NBPB + ld;
        if (node >= N_NODES) break;
        int j = soffs[ld];
        const int e = j + scnt[ld];
        float s = 0.f;
        for (; j + 4 <= e; j += 4) {
            int2 p0 = eSort[j], p1 = eSort[j + 1], p2 = eSort[j + 2], p3 = eSort[j + 3];
            float h0 = __bfloat162float(hb[(size_t)(p0.x & 0x3FFFF) * NC + c]);
            float h1 = __bfloat162float(hb[(size_t)(p1.x & 0x3FFFF) * NC + c]);
            float h2 = __bfloat162float(hb[(size_t)(p2.x & 0x3FFFF) * NC + c]);
            float h3 = __bfloat162float(hb[(size_t)(p3.x & 0x3FFFF) * NC + c]);
            s = fmaf(h0, __int_as_float(p0.y), s);
            s = fmaf(h1, __int_as_float(p1.y), s);
            s = fmaf(h2, __int_as_float(p2.y), s);
            s = fmaf(h3, __int_as_float(p3.y), s);
        }
        for (; j < e; ++j) {
            int2 p = eSort[j];
            float hv = __bfloat162float(hb[(size_t)(p.x & 0x3FFFF) * NC + c]);
            s = fmaf(hv, __int_as_float(p.y), s);
        }
        y[(size_t)node * NC + c] = s;
        scol += s;
    }

    red[tid] = scol;
    __syncthreads();
    if (tid < 32) {
        float t = 0.f;
        #pragma unroll
        for (int jj = 0; jj < 16; ++jj) t += red[tid + 32 * jj];
        atomAddF(&colsum[tid], t);
    }
}

// ---------------------------------------------------------------------------
// Fallback path (small workspace): standalone linear + atomic scatter
// ---------------------------------------------------------------------------
__global__ __launch_bounds__(256, 3) void k_linear_fb(
    const float* __restrict__ x, const float* __restrict__ Wmat,
    const float* __restrict__ bias, const float* __restrict__ u_sum,
    ushort* __restrict__ h_bf, float* __restrict__ S1, float* __restrict__ S2)
{
    __shared__ float lds_s1[4][32];
    __shared__ float lds_s2[4];

    const int lane = threadIdx.x & 63;
    const int wv   = threadIdx.x >> 6;
    const int lr   = lane & 15;
    const int kc   = lane >> 4;

    bf16x8 bfr[8][2];
    #pragma unroll
    for (int ct = 0; ct < 2; ++ct) {
        const float* wp = Wmat + (size_t)(ct * 16 + lr) * FEATS + kc * 8;
        #pragma unroll
        for (int kt = 0; kt < 8; ++kt) {
            f32x4 v0 = *(const f32x4*)(wp + kt * 32);
            f32x4 v1 = *(const f32x4*)(wp + kt * 32 + 4);
            bf16x8 b;
            b[0]=f2bf(v0.x); b[1]=f2bf(v0.y); b[2]=f2bf(v0.z); b[3]=f2bf(v0.w);
            b[4]=f2bf(v1.x); b[5]=f2bf(v1.y); b[6]=f2bf(v1.z); b[7]=f2bf(v1.w);
            bfr[kt][ct] = b;
        }
    }

    const float bias0 = bias[lr], bias1 = bias[16 + lr];
    const float invn = 1.0f / (float)N_NODES;
    float s1_0 = 0.f, s1_1 = 0.f, s2 = 0.f;

    const int ntiles = N_NODES / 16;
    for (int t = blockIdx.x * 4 + wv; t < ntiles; t += gridDim.x * 4) {
        const int base = t * 16;
        const float* xp = x + (size_t)(base + lr) * FEATS + kc * 8;
        f32x4 acc0 = {bias0, bias0, bias0, bias0};
        f32x4 acc1 = {bias1, bias1, bias1, bias1};
        #pragma unroll
        for (int kt = 0; kt < 8; ++kt) {
            f32x4 v0 = *(const f32x4*)(xp + kt * 32);
            f32x4 v1 = *(const f32x4*)(xp + kt * 32 + 4);
            bf16x8 a;
            a[0]=f2bf(v0.x); a[1]=f2bf(v0.y); a[2]=f2bf(v0.z); a[3]=f2bf(v0.w);
            a[4]=f2bf(v1.x); a[5]=f2bf(v1.y); a[6]=f2bf(v1.z); a[7]=f2bf(v1.w);
            acc0 = __builtin_amdgcn_mfma_f32_16x16x32_bf16(a, bfr[kt][0], acc0, 0, 0, 0);
            acc1 = __builtin_amdgcn_mfma_f32_16x16x32_bf16(a, bfr[kt][1], acc1, 0, 0, 0);
        }
        #pragma unroll
        for (int i = 0; i < 4; ++i) {
            const int row = base + kc * 4 + i;
            h_bf[(size_t)row * NC + lr]      = (ushort)f2bf(acc0[i]);
            h_bf[(size_t)row * NC + 16 + lr] = (ushort)f2bf(acc1[i]);
            const float um = u_sum[row] * invn;
            float a0 = um * acc0[i], a1 = um * acc1[i];
            s1_0 += a0; s1_1 += a1;
            s2 += a0 * a0 + a1 * a1;
        }
    }

    s1_0 += __shfl_xor(s1_0, 16); s1_0 += __shfl_xor(s1_0, 32);
    s1_1 += __shfl_xor(s1_1, 16); s1_1 += __shfl_xor(s1_1, 32);
    #pragma unroll
    for (int off = 1; off < 64; off <<= 1) s2 += __shfl_xor(s2, off);
    if (lane < 16) { lds_s1[wv][lr] = s1_0; lds_s1[wv][16 + lr] = s1_1; }
    if (lane == 0) lds_s2[wv] = s2;
    __syncthreads();
    if (threadIdx.x < 32) {
        float t4 = lds_s1[0][threadIdx.x] + lds_s1[1][threadIdx.x]
                 + lds_s1[2][threadIdx.x] + lds_s1[3][threadIdx.x];
        atomAddF(&S1[threadIdx.x], t4);
    }
    if (threadIdx.x == 32)
        atomAddF(S2, lds_s2[0] + lds_s2[1] + lds_s2[2] + lds_s2[3]);
}

__global__ __launch_bounds__(256) void k_scatter_atomic(
    const ushort* __restrict__ h_bf, const float* __restrict__ w,
    const int* __restrict__ src, const int* __restrict__ dst,
    float* __restrict__ y)
{
    const __hip_bfloat16* hb = (const __hip_bfloat16*)h_bf;
    const long long total  = (long long)N_EDGES * NC;
    const long long stride = (long long)gridDim.x * 256;
    for (long long i = (long long)blockIdx.x * 256 + threadIdx.x;
         i < total; i += stride) {
        const int e = (int)(i >> 5);
        const int c = (int)(i & 31);
        float hv = __bfloat162float(hb[(size_t)src[e] * NC + c]);
        atomAddF(&y[(size_t)dst[e] * NC + c], hv * w[e]);
    }
}

__global__ __launch_bounds__(256) void k_colsum(
    const float* __restrict__ y, float* __restrict__ colsum)
{
    __shared__ float red[256];
    const long long total  = (long long)N_NODES * NC;
    const long long stride = (long long)gridDim.x * 256;
    float s = 0.f;
    for (long long i = (long long)blockIdx.x * 256 + threadIdx.x;
         i < total; i += stride)
        s += y[i];
    red[threadIdx.x] = s;
    __syncthreads();
    if (threadIdx.x < 32) {
        float t = 0.f;
        #pragma unroll
        for (int j = 0; j < 8; ++j) t += red[threadIdx.x + 32 * j];
        atomAddF(&colsum[threadIdx.x], t);
    }
}

// ---------------------------------------------------------------------------
// loss; acc: [0..31] colsum_y, [32..63] S1, [64] S2
// ---------------------------------------------------------------------------
__global__ void k_final(const float* __restrict__ acc, float* __restrict__ loss_out)
{
    double cross = 0.0, msq = 0.0;
    for (int c = 0; c < NC; ++c) {
        double m = (double)acc[c] / (double)N_NODES;
        cross += m * (double)acc[32 + c];
        msq   += m * m;
    }
    double loss = ((double)acc[64] - 2.0 * cross + (double)N_NODES * msq)
                  / ((double)N_NODES * (double)NC);
    *loss_out = (float)loss;
}

extern "C" void kernel_launch(void* const* d_in, const int* in_sizes, int n_in,
                              void* d_out, int out_size, void* d_ws, size_t ws_size,
                              hipStream_t stream)
{
    const float* x   = (const float*)d_in[0];
    const float* w   = (const float*)d_in[1];
    const float* u   = (const float*)d_in[2];
    const float* Wm  = (const float*)d_in[3];
    const float* Wb  = (const float*)d_in[4];
    const int*   src = (const int*)d_in[5];
    const int*   dst = (const int*)d_in[6];

    float* out = (float*)d_out;                  // y [N*32] then loss [1]

    uint8_t* w8 = (uint8_t*)d_ws;
    float*  acc  = (float*)w8;                   // 256 floats (1 KB)
    int*    pos  = (int*)(w8 + 1024);            // BUCKETS counts (padded 8 KB)
    ushort* h_bf = (ushort*)(w8 + 1024 + 8192);  // 12.8 MB
    int2*   bucketed = (int2*)(w8 + 1024 + 8192 + (size_t)N_NODES * NC * 2); // 32 MB

    const size_t need = 1024 + 8192 + (size_t)N_NODES * NC * 2
                      + (size_t)BUCKETS * CAP * 8;

    // zero acc (1 KB) + pos (8 KB) in one memset
    hipMemsetAsync(w8, 0, 1024 + 8192, stream);

    if (ws_size >= need) {
        k_fused  <<<2 * BKT_BLOCKS + (LIN_BLOCKS - BKT_BLOCKS), 512, 0, stream>>>(
            x, Wm, Wb, u, h_bf, acc + 32, acc + 64, src, w, dst, pos, bucketed);
        k_breduce<<<BUCKETS, 512, 0, stream>>>(bucketed, pos, h_bf, out, acc);
    } else {
        hipMemsetAsync(d_out, 0, (size_t)out_size * sizeof(float), stream);
        k_linear_fb     <<<2048, 256, 0, stream>>>(x, Wm, Wb, u, h_bf, acc + 32, acc + 64);
        k_scatter_atomic<<<8192, 256, 0, stream>>>(h_bf, w, src, dst, out);
        k_colsum        <<<2048, 256, 0, stream>>>(out, acc);
    }

    k_final<<<1, 1, 0, stream>>>(acc, out + (size_t)N_NODES * NC);
}